// Round 5
// baseline (341.697 us; speedup 1.0000x reference)
//
#include <hip/hip_runtime.h>
#include <math.h>

// B=4096, IN=1024, H=2048, OUT=1024
// cosmic layer == broadcast prob[r] = (1/H)*(prod_{d,k} cos(cw[d,r,k]))^2
// Network = 6 fp16-MFMA GEMMs (32x32x16) with fused bias/relu/tanh epilogues.
//
// GEMM geometry (r5): BM x 128 tile, BK=32, 256 thr (4 waves 2Mx2N),
// per-wave 128x64 output (4x2 reg blocking -> reads/MFMA=0.75, the LDS-BW
// lever), tri-buffered LDS (72 KB) -> 2 blocks/CU for cross-block overlap,
// counted vmcnt (T4), counted lgkmcnt per k-step cluster (rule 18 fences),
// setprio (T5), XOR-swizzled LDS both-sides (T2, rule 21), XCD swizzle (T1).

typedef _Float16 f16;
typedef _Float16 f16x8 __attribute__((ext_vector_type(8)));
typedef _Float16 f16x4 __attribute__((ext_vector_type(4)));
typedef float f32x16 __attribute__((ext_vector_type(16)));

#define GLD16(gp, lp) __builtin_amdgcn_global_load_lds( \
    (const __attribute__((address_space(1))) unsigned int*)(gp), \
    (__attribute__((address_space(3))) unsigned int*)(lp), 16, 0, 0)

// ---------------- fp32 -> fp16 cast ----------------
__global__ void cast_f32_f16(const float* __restrict__ in, f16* __restrict__ out, int n4) {
  int i = blockIdx.x * 256 + threadIdx.x;
  if (i < n4) {
    float4 v = ((const float4*)in)[i];
    f16x4 o = { (f16)v.x, (f16)v.y, (f16)v.z, (f16)v.w };
    ((f16x4*)out)[i] = o;
  }
}

// ------- merged cast+transpose, vectorized: 32(K) x 64(N) f32 tiles -------
struct TD { const float* src; f16* dst; int K; int N; };
struct TD6 { TD d[6]; };

__global__ void cast_transpose6(TD6 a) {
  TD d = a.d[blockIdx.z];
  const int bx = blockIdx.x * 64;   // N
  const int by = blockIdx.y * 32;   // K
  if (bx >= d.N || by >= d.K) return;
  __shared__ float tile[32][68];
  const int t = threadIdx.x;
#pragma unroll
  for (int pass = 0; pass < 2; ++pass) {
    int idx = t + pass * 256;       // 0..511
    int row = idx >> 4;             // 0..31
    int c4  = (idx & 15) * 4;       // 0..60
    float4 v = *(const float4*)&d.src[(size_t)(by + row) * d.N + bx + c4];
    *(float4*)&tile[row][c4] = v;
  }
  __syncthreads();
  const int nl = t >> 2;            // 0..63
  const int k8 = (t & 3) * 8;       // 0..24
  f16x8 o;
#pragma unroll
  for (int j = 0; j < 8; ++j) o[j] = (f16)tile[k8 + j][nl];
  *(f16x8*)&d.dst[(size_t)(bx + nl) * d.K + by + k8] = o;
}

// ---------------- cosmic prob, 2-pass ----------------
__global__ void cosmic_pp(const float* __restrict__ cw, float* __restrict__ pp, int H) {
  int i = blockIdx.x * 256 + threadIdx.x;   // i = d*H + r
  if (i >= 8 * H) return;
  const float* a = cw + (size_t)i * H;      // cw[d][r][0..2]
  pp[i] = cosf(a[0]) * cosf(a[1]) * cosf(a[2]);
}
__global__ void cosmic_fin(const float* __restrict__ pp, float* __restrict__ prob, int H) {
  int r = blockIdx.x * 256 + threadIdx.x;
  if (r >= H) return;
  float p = 1.0f;
#pragma unroll
  for (int d = 0; d < 8; ++d) p *= pp[d * H + r];
  prob[r] = p * p / (float)H;
}

// ---------------- fp16 MFMA GEMM (32x32x16) ----------------
// A: (M,K) f16 row-major. BT: (N,K) f16 row-major.
// EPI 0: relu->f16  1: tanh(+prob)->f16  2: relu->f32
template <int EPI, int BM>
__global__ __launch_bounds__(256, 2)
void gemm_f16(const f16* __restrict__ A, const f16* __restrict__ BT,
              const float* __restrict__ bias, const float* __restrict__ prob,
              f16* __restrict__ Ch, float* __restrict__ Cf,
              int M, int N, int K, int GX) {
  constexpr int ASZ = BM * 32;          // f16 per A buffer (BK=32)
  constexpr int BSZ = 128 * 32;         // f16 per B buffer
  constexpr int MB  = BM / 64;          // 32-row A frags per wave (4 or 2)
  constexpr int RA  = BM / 64;          // A stage rounds (4 or 2), 256thr*16B=4KB/round
  constexpr int NLD = RA + 2;           // VMEM issues per tile
  __shared__ f16 lds[3 * (ASZ + BSZ)];
  f16* As = lds;
  f16* Bs = lds + 3 * ASZ;

  const int t = threadIdx.x;

  // XCD-aware swizzle (nwg % 8 == 0 for all our grids)
  const int nwg = gridDim.x;
  const int bid = blockIdx.x;
  const int swz = (bid & 7) * (nwg >> 3) + (bid >> 3);
  const int bx = swz % GX;
  const int by = swz / GX;
  const int m0 = by * BM;
  const int n0 = bx * 128;

  // staging: LDS dest linear; XOR swizzle (chunk ^= row&3, 4 chunks/row)
  // pre-applied to the GLOBAL source (rule 21).
  auto stage_all = [&](int kt, int buf) {
    const int k0 = kt << 5;
#pragma unroll
    for (int q = 0; q < RA; ++q) {
      int F = q * 2048 + t * 8;
      int r = F >> 5, c = (F >> 3) & 3;
      GLD16(A + (size_t)(m0 + r) * K + k0 + ((c ^ (r & 3)) << 3), As + buf * ASZ + F);
    }
#pragma unroll
    for (int q = 0; q < 2; ++q) {
      int F = q * 2048 + t * 8;
      int r = F >> 5, c = (F >> 3) & 3;
      GLD16(BT + (size_t)(n0 + r) * K + k0 + ((c ^ (r & 3)) << 3), Bs + buf * BSZ + F);
    }
  };

  const int wave = t >> 6, lane = t & 63;
  const int wr = wave >> 1, wc = wave & 1;  // 2M x 2N waves; wave = 128x64 (BM=256)
  const int rc = lane & 31, hi = lane >> 5;

  f32x16 acc[MB][2] = {};

  const int nt = K >> 5;
  stage_all(0, 0);
  stage_all(1, 1);
  int cur = 0;
  for (int kt = 0; kt < nt; ++kt) {
    if (kt + 1 < nt) {
      // own tile-kt loads retired; tile kt+1's NLD stay in flight
      asm volatile("s_waitcnt vmcnt(%0)" :: "i"(NLD) : "memory");
    } else {
      asm volatile("s_waitcnt vmcnt(0)" ::: "memory");
    }
    __builtin_amdgcn_s_barrier();
    if (kt + 2 < nt) {
      int sb = cur + 2; if (sb >= 3) sb -= 3;
      stage_all(kt + 2, sb);              // issue prefetch first (longest latency)
    }

    const f16* Ab = As + cur * ASZ;
    const f16* Bb = Bs + cur * BSZ;
    f16x8 a[2][MB], b[2][2];
    // k-step 0 reads, order-pinned, then k-step 1 reads
#pragma unroll
    for (int s = 0; s < 2; ++s) {
      const int cc = s * 2 + hi;          // 16B chunk (4 per 32-f16 row)
#pragma unroll
      for (int mb = 0; mb < MB; ++mb) {
        int row = wr * (BM / 2) + mb * 32 + rc;
        a[s][mb] = *(const f16x8*)&Ab[row * 32 + ((cc ^ (row & 3)) << 3)];
      }
#pragma unroll
      for (int nb = 0; nb < 2; ++nb) {
        int row = wc * 64 + nb * 32 + rc;
        b[s][nb] = *(const f16x8*)&Bb[row * 32 + ((cc ^ (row & 3)) << 3)];
      }
      __builtin_amdgcn_sched_barrier(0);  // pin: step-0 reads issue before step-1
    }
    // cluster 0: wait only k-step-0 reads (6 of 12), k-step-1 hides under MFMA
    asm volatile("s_waitcnt lgkmcnt(%0)" :: "i"(MB + 2) : "memory");
    __builtin_amdgcn_sched_barrier(0);
    __builtin_amdgcn_s_setprio(1);
#pragma unroll
    for (int mb = 0; mb < MB; ++mb)
#pragma unroll
      for (int nb = 0; nb < 2; ++nb)
        acc[mb][nb] = __builtin_amdgcn_mfma_f32_32x32x16_f16(a[0][mb], b[0][nb], acc[mb][nb], 0, 0, 0);
    __builtin_amdgcn_s_setprio(0);
    asm volatile("s_waitcnt lgkmcnt(0)" ::: "memory");
    __builtin_amdgcn_sched_barrier(0);
    __builtin_amdgcn_s_setprio(1);
#pragma unroll
    for (int mb = 0; mb < MB; ++mb)
#pragma unroll
      for (int nb = 0; nb < 2; ++nb)
        acc[mb][nb] = __builtin_amdgcn_mfma_f32_32x32x16_f16(a[1][mb], b[1][nb], acc[mb][nb], 0, 0, 0);
    __builtin_amdgcn_s_setprio(0);
    cur = (cur + 1 == 3) ? 0 : cur + 1;
  }

  // epilogue: 32x32 C/D layout col=lane&31, row=(r&3)+8*(r>>2)+4*(lane>>5)
#pragma unroll
  for (int nb = 0; nb < 2; ++nb) {
    const int col = n0 + wc * 64 + nb * 32 + rc;
    float bn = bias[col];
    if (EPI == 1) bn += prob[col];
#pragma unroll
    for (int mb = 0; mb < MB; ++mb) {
      const int rbase = m0 + wr * (BM / 2) + mb * 32 + 4 * hi;
#pragma unroll
      for (int r = 0; r < 16; ++r) {
        const int row = rbase + (r & 3) + 8 * (r >> 2);
        float v = acc[mb][nb][r] + bn;
        if (EPI == 1) v = tanhf(v);
        else v = fmaxf(v, 0.0f);
        if (EPI == 2) Cf[(size_t)row * N + col] = v;
        else Ch[(size_t)row * N + col] = (f16)v;
      }
    }
  }
}

extern "C" void kernel_launch(void* const* d_in, const int* in_sizes, int n_in,
                              void* d_out, int out_size, void* d_ws, size_t ws_size,
                              hipStream_t stream) {
  const float* x   = (const float*)d_in[0];
  const float* W0  = (const float*)d_in[1];
  const float* b0  = (const float*)d_in[2];
  const float* W1  = (const float*)d_in[3];
  const float* b1  = (const float*)d_in[4];
  const float* cw1 = (const float*)d_in[5];
  const float* KW1 = (const float*)d_in[7];
  const float* Kb1 = (const float*)d_in[8];
  const float* W2  = (const float*)d_in[9];
  const float* b2  = (const float*)d_in[10];
  const float* cw2 = (const float*)d_in[11];
  const float* KW2 = (const float*)d_in[13];
  const float* Kb2 = (const float*)d_in[14];
  const float* W3  = (const float*)d_in[15];
  const float* b3  = (const float*)d_in[16];

  const int B = 4096, IN = 1024, H = 2048, OUT = 1024;

  char* ws = (char*)d_ws;
  size_t off = 0;
  auto alloc = [&](size_t bytes) {
    char* p = ws + off;
    off = (off + bytes + 255) & ~(size_t)255;
    return p;
  };
  f16* xh    = (f16*)alloc((size_t)B * IN * 2);
  f16* W0T   = (f16*)alloc((size_t)H * IN * 2);
  f16* W1T   = (f16*)alloc((size_t)H * H * 2);
  f16* KW1T  = (f16*)alloc((size_t)H * H * 2);
  f16* W2T   = (f16*)alloc((size_t)H * H * 2);
  f16* KW2T  = (f16*)alloc((size_t)H * H * 2);
  f16* W3T   = (f16*)alloc((size_t)OUT * H * 2);
  f16* hA    = (f16*)alloc((size_t)B * H * 2);
  f16* hB    = (f16*)alloc((size_t)B * H * 2);
  float* p1  = (float*)alloc((size_t)H * 4);
  float* p2  = (float*)alloc((size_t)H * 4);
  float* pp  = (float*)alloc((size_t)8 * H * 4);
  (void)ws_size;

  cast_f32_f16<<<(B * IN / 4 + 255) / 256, 256, 0, stream>>>(x, xh, B * IN / 4);

  TD6 td;
  td.d[0] = { W0,  W0T,  IN, H };
  td.d[1] = { W1,  W1T,  H,  H };
  td.d[2] = { KW1, KW1T, H,  H };
  td.d[3] = { W2,  W2T,  H,  H };
  td.d[4] = { KW2, KW2T, H,  H };
  td.d[5] = { W3,  W3T,  H,  OUT };
  cast_transpose6<<<dim3(H / 64, H / 32, 6), 256, 0, stream>>>(td);

  cosmic_pp<<<(8 * H + 255) / 256, 256, 0, stream>>>(cw1, pp, H);
  cosmic_fin<<<(H + 255) / 256, 256, 0, stream>>>(pp, p1, H);
  cosmic_pp<<<(8 * H + 255) / 256, 256, 0, stream>>>(cw2, pp, H);
  cosmic_fin<<<(H + 255) / 256, 256, 0, stream>>>(pp, p2, H);

  // G0-G4: BM=256 (grid 16x16=256). G5: BM=128 (grid 32x8=256).
  {
    int gx = H / 128, gy = B / 256;
    dim3 g(gx * gy);
    gemm_f16<0, 256><<<g, 256, 0, stream>>>(xh, W0T, b0,  nullptr, hA, nullptr, B, H, IN, gx);
    gemm_f16<0, 256><<<g, 256, 0, stream>>>(hA, W1T, b1,  nullptr, hB, nullptr, B, H, H,  gx);
    gemm_f16<1, 256><<<g, 256, 0, stream>>>(hB, KW1T, Kb1, p1,     hA, nullptr, B, H, H,  gx);
    gemm_f16<0, 256><<<g, 256, 0, stream>>>(hA, W2T, b2,  nullptr, hB, nullptr, B, H, H,  gx);
    gemm_f16<1, 256><<<g, 256, 0, stream>>>(hB, KW2T, Kb2, p2,     hA, nullptr, B, H, H,  gx);
  }
  {
    int gx = OUT / 128, gy = B / 128;
    dim3 g(gx * gy);
    gemm_f16<2, 128><<<g, 256, 0, stream>>>(hA, W3T, b3, nullptr, nullptr, (float*)d_out, B, OUT, H, gx);
  }
}

// Round 6
// 242.077 us; speedup vs baseline: 1.4115x; 1.4115x over previous
//
#include <hip/hip_runtime.h>
#include <math.h>

// B=4096, IN=1024, H=2048, OUT=1024
// cosmic layer == broadcast prob[r] = (1/H)*(prod_{d,k} cos(cw[d,r,k]))^2
// Network = 6 fp16-MFMA GEMMs (16x16x32) with fused bias/relu/tanh epilogues.
//
// GEMM geometry (r6 = m201's wave shape on BN=128 grid): BM x 128, BK=64,
// 256 thr (4 waves 2Mx2N), per-wave 128x64 (M_rep=8, N_rep=4, acc=128 VGPR),
// 42.7 FLOP per LDS byte (1.33x r3), 16-row frag reads -> 2-way banks = free.
// Tri-buffered LDS (144 KB), counted vmcnt (T4), 2-cluster lgkm pipeline
// (rule 18 fences), setprio (T5), XOR-swizzle both-sides (T2/21), XCD (T1).

typedef _Float16 f16;
typedef _Float16 f16x8 __attribute__((ext_vector_type(8)));
typedef _Float16 f16x4 __attribute__((ext_vector_type(4)));
typedef float f32x4 __attribute__((ext_vector_type(4)));

#define GLD16(gp, lp) __builtin_amdgcn_global_load_lds( \
    (const __attribute__((address_space(1))) unsigned int*)(gp), \
    (__attribute__((address_space(3))) unsigned int*)(lp), 16, 0, 0)

__device__ __forceinline__ float tanh_fast(float x) {
  // 1 - 2/(e^{2x}+1); exact at +-inf, rel err ~1e-6
  return 1.0f - 2.0f / (__expf(2.0f * x) + 1.0f);
}

// ---------------- fp32 -> fp16 cast ----------------
__global__ void cast_f32_f16(const float* __restrict__ in, f16* __restrict__ out, int n4) {
  int i = blockIdx.x * 256 + threadIdx.x;
  if (i < n4) {
    float4 v = ((const float4*)in)[i];
    f16x4 o = { (f16)v.x, (f16)v.y, (f16)v.z, (f16)v.w };
    ((f16x4*)out)[i] = o;
  }
}

// ------- merged cast+transpose, vectorized: 32(K) x 64(N) f32 tiles -------
struct TD { const float* src; f16* dst; int K; int N; };
struct TD6 { TD d[6]; };

__global__ void cast_transpose6(TD6 a) {
  TD d = a.d[blockIdx.z];
  const int bx = blockIdx.x * 64;   // N
  const int by = blockIdx.y * 32;   // K
  if (bx >= d.N || by >= d.K) return;
  __shared__ float tile[32][68];
  const int t = threadIdx.x;
#pragma unroll
  for (int pass = 0; pass < 2; ++pass) {
    int idx = t + pass * 256;
    int row = idx >> 4;
    int c4  = (idx & 15) * 4;
    float4 v = *(const float4*)&d.src[(size_t)(by + row) * d.N + bx + c4];
    *(float4*)&tile[row][c4] = v;
  }
  __syncthreads();
  const int nl = t >> 2;
  const int k8 = (t & 3) * 8;
  f16x8 o;
#pragma unroll
  for (int j = 0; j < 8; ++j) o[j] = (f16)tile[k8 + j][nl];
  *(f16x8*)&d.dst[(size_t)(bx + nl) * d.K + by + k8] = o;
}

// ---------------- cosmic prob, 2-pass ----------------
__global__ void cosmic_pp(const float* __restrict__ cw, float* __restrict__ pp, int H) {
  int i = blockIdx.x * 256 + threadIdx.x;   // i = d*H + r
  if (i >= 8 * H) return;
  const float* a = cw + (size_t)i * H;
  pp[i] = cosf(a[0]) * cosf(a[1]) * cosf(a[2]);
}
__global__ void cosmic_fin(const float* __restrict__ pp, float* __restrict__ prob, int H) {
  int r = blockIdx.x * 256 + threadIdx.x;
  if (r >= H) return;
  float p = 1.0f;
#pragma unroll
  for (int d = 0; d < 8; ++d) p *= pp[d * H + r];
  prob[r] = p * p / (float)H;
}

// ---------------- fp16 MFMA GEMM (16x16x32) ----------------
// A: (M,K) f16 row-major. BT: (N,K) f16 row-major.
// EPI 0: relu->f16  1: tanh(+prob)->f16  2: relu->f32
template <int EPI, int BM>
__global__ __launch_bounds__(256, 1)
void gemm_f16(const f16* __restrict__ A, const f16* __restrict__ BT,
              const float* __restrict__ bias, const float* __restrict__ prob,
              f16* __restrict__ Ch, float* __restrict__ Cf,
              int M, int N, int K, int GX) {
  constexpr int ASZ = BM * 64;          // f16 per A buffer (BK=64)
  constexpr int BSZ = 128 * 64;         // f16 per B buffer
  constexpr int MR  = BM / 32;          // A frag repeats per wave (8 or 4)
  constexpr int RA  = BM / 32;          // A stage rounds (256thr*8f16=2048=32rows)
  constexpr int NLD = RA + 4;           // VMEM issues per tile (A + 4 B rounds)
  __shared__ f16 lds[3 * (ASZ + BSZ)];  // 144 KB (BM=256) / 96 KB (BM=128)
  f16* As = lds;
  f16* Bs = lds + 3 * ASZ;

  const int t = threadIdx.x;

  // XCD-aware swizzle (nwg % 8 == 0 for all our grids)
  const int nwg = gridDim.x;
  const int bid = blockIdx.x;
  const int swz = (bid & 7) * (nwg >> 3) + (bid >> 3);
  const int bx = swz % GX;
  const int by = swz / GX;
  const int m0 = by * BM;
  const int n0 = bx * 128;

  // staging: LDS dest linear; XOR swizzle (chunk ^= row&7, 8 chunks/row)
  // pre-applied to the GLOBAL source (rule 21).
  auto stage_all = [&](int kt, int buf) {
    const int k0 = kt << 6;
#pragma unroll
    for (int q = 0; q < RA; ++q) {
      int F = q * 2048 + t * 8;
      int r = F >> 6, c = (F >> 3) & 7;
      GLD16(A + (size_t)(m0 + r) * K + k0 + ((c ^ (r & 7)) << 3), As + buf * ASZ + F);
    }
#pragma unroll
    for (int q = 0; q < 4; ++q) {
      int F = q * 2048 + t * 8;
      int r = F >> 6, c = (F >> 3) & 7;
      GLD16(BT + (size_t)(n0 + r) * K + k0 + ((c ^ (r & 7)) << 3), Bs + buf * BSZ + F);
    }
  };

  const int wave = t >> 6, lane = t & 63;
  const int wr = wave >> 1, wc = wave & 1;  // 2M x 2N waves; wave = (BM/2) x 64
  const int l16 = lane & 15, kq = lane >> 4;  // frag: row l16, k-chunk kq

  f32x4 acc[MR][4] = {};

  const int nt = K >> 6;
  stage_all(0, 0);
  stage_all(1, 1);
  int cur = 0;
  for (int kt = 0; kt < nt; ++kt) {
    if (kt + 1 < nt) {
      asm volatile("s_waitcnt vmcnt(%0)" :: "i"(NLD) : "memory");  // tile kt done
    } else {
      asm volatile("s_waitcnt vmcnt(0)" ::: "memory");
    }
    __builtin_amdgcn_s_barrier();
    if (kt + 2 < nt) {
      int sb = cur + 2; if (sb >= 3) sb -= 3;
      stage_all(kt + 2, sb);              // prefetch issue overlaps compute
    }

    const f16* Ab = As + cur * ASZ;
    const f16* Bb = Bs + cur * BSZ;
    f16x8 a[2][MR], b[2][4];
#pragma unroll
    for (int s = 0; s < 2; ++s) {
      const int cc = s * 4 + kq;          // 16B chunk (8 per 64-f16 row)
#pragma unroll
      for (int mr = 0; mr < MR; ++mr) {
        int row = wr * (BM / 2) + mr * 16 + l16;
        a[s][mr] = *(const f16x8*)&Ab[row * 64 + ((cc ^ (row & 7)) << 3)];
      }
#pragma unroll
      for (int nr = 0; nr < 4; ++nr) {
        int row = wc * 64 + nr * 16 + l16;
        b[s][nr] = *(const f16x8*)&Bb[row * 64 + ((cc ^ (row & 7)) << 3)];
      }
      __builtin_amdgcn_sched_barrier(0);  // pin issue order: step0 before step1
    }
    // cluster 0: wait step-0's reads (step-1's 12 still outstanding)
    asm volatile("s_waitcnt lgkmcnt(%0)" :: "i"(MR + 4) : "memory");
    __builtin_amdgcn_sched_barrier(0);
    __builtin_amdgcn_s_setprio(1);
#pragma unroll
    for (int mr = 0; mr < MR; ++mr)
#pragma unroll
      for (int nr = 0; nr < 4; ++nr)
        acc[mr][nr] = __builtin_amdgcn_mfma_f32_16x16x32_f16(a[0][mr], b[0][nr], acc[mr][nr], 0, 0, 0);
    __builtin_amdgcn_s_setprio(0);
    asm volatile("s_waitcnt lgkmcnt(0)" ::: "memory");
    __builtin_amdgcn_sched_barrier(0);
    __builtin_amdgcn_s_setprio(1);
#pragma unroll
    for (int mr = 0; mr < MR; ++mr)
#pragma unroll
      for (int nr = 0; nr < 4; ++nr)
        acc[mr][nr] = __builtin_amdgcn_mfma_f32_16x16x32_f16(a[1][mr], b[1][nr], acc[mr][nr], 0, 0, 0);
    __builtin_amdgcn_s_setprio(0);
    cur = (cur + 1 == 3) ? 0 : cur + 1;
  }

  // epilogue: 16x16 C/D layout col=lane&15, row=(lane>>4)*4+q
#pragma unroll
  for (int nr = 0; nr < 4; ++nr) {
    const int col = n0 + wc * 64 + nr * 16 + l16;
    float bn = bias[col];
    if (EPI == 1) bn += prob[col];
#pragma unroll
    for (int mr = 0; mr < MR; ++mr) {
      const int rbase = m0 + wr * (BM / 2) + mr * 16 + kq * 4;
#pragma unroll
      for (int q = 0; q < 4; ++q) {
        float v = acc[mr][nr][q] + bn;
        if (EPI == 1) v = tanh_fast(v);
        else v = fmaxf(v, 0.0f);
        if (EPI == 2) Cf[(size_t)(rbase + q) * N + col] = v;
        else Ch[(size_t)(rbase + q) * N + col] = (f16)v;
      }
    }
  }
}

extern "C" void kernel_launch(void* const* d_in, const int* in_sizes, int n_in,
                              void* d_out, int out_size, void* d_ws, size_t ws_size,
                              hipStream_t stream) {
  const float* x   = (const float*)d_in[0];
  const float* W0  = (const float*)d_in[1];
  const float* b0  = (const float*)d_in[2];
  const float* W1  = (const float*)d_in[3];
  const float* b1  = (const float*)d_in[4];
  const float* cw1 = (const float*)d_in[5];
  const float* KW1 = (const float*)d_in[7];
  const float* Kb1 = (const float*)d_in[8];
  const float* W2  = (const float*)d_in[9];
  const float* b2  = (const float*)d_in[10];
  const float* cw2 = (const float*)d_in[11];
  const float* KW2 = (const float*)d_in[13];
  const float* Kb2 = (const float*)d_in[14];
  const float* W3  = (const float*)d_in[15];
  const float* b3  = (const float*)d_in[16];

  const int B = 4096, IN = 1024, H = 2048, OUT = 1024;

  char* ws = (char*)d_ws;
  size_t off = 0;
  auto alloc = [&](size_t bytes) {
    char* p = ws + off;
    off = (off + bytes + 255) & ~(size_t)255;
    return p;
  };
  f16* xh    = (f16*)alloc((size_t)B * IN * 2);
  f16* W0T   = (f16*)alloc((size_t)H * IN * 2);
  f16* W1T   = (f16*)alloc((size_t)H * H * 2);
  f16* KW1T  = (f16*)alloc((size_t)H * H * 2);
  f16* W2T   = (f16*)alloc((size_t)H * H * 2);
  f16* KW2T  = (f16*)alloc((size_t)H * H * 2);
  f16* W3T   = (f16*)alloc((size_t)OUT * H * 2);
  f16* hA    = (f16*)alloc((size_t)B * H * 2);
  f16* hB    = (f16*)alloc((size_t)B * H * 2);
  float* p1  = (float*)alloc((size_t)H * 4);
  float* p2  = (float*)alloc((size_t)H * 4);
  float* pp  = (float*)alloc((size_t)8 * H * 4);
  (void)ws_size;

  cast_f32_f16<<<(B * IN / 4 + 255) / 256, 256, 0, stream>>>(x, xh, B * IN / 4);

  TD6 td;
  td.d[0] = { W0,  W0T,  IN, H };
  td.d[1] = { W1,  W1T,  H,  H };
  td.d[2] = { KW1, KW1T, H,  H };
  td.d[3] = { W2,  W2T,  H,  H };
  td.d[4] = { KW2, KW2T, H,  H };
  td.d[5] = { W3,  W3T,  H,  OUT };
  cast_transpose6<<<dim3(H / 64, H / 32, 6), 256, 0, stream>>>(td);

  cosmic_pp<<<(8 * H + 255) / 256, 256, 0, stream>>>(cw1, pp, H);
  cosmic_fin<<<(H + 255) / 256, 256, 0, stream>>>(pp, p1, H);
  cosmic_pp<<<(8 * H + 255) / 256, 256, 0, stream>>>(cw2, pp, H);
  cosmic_fin<<<(H + 255) / 256, 256, 0, stream>>>(pp, p2, H);

  // G0-G4: BM=256 (grid 16x16=256). G5: BM=128 (grid 8x32=256).
  {
    int gx = H / 128, gy = B / 256;
    dim3 g(gx * gy);
    gemm_f16<0, 256><<<g, 256, 0, stream>>>(xh, W0T, b0,  nullptr, hA, nullptr, B, H, IN, gx);
    gemm_f16<0, 256><<<g, 256, 0, stream>>>(hA, W1T, b1,  nullptr, hB, nullptr, B, H, H,  gx);
    gemm_f16<1, 256><<<g, 256, 0, stream>>>(hB, KW1T, Kb1, p1,     hA, nullptr, B, H, H,  gx);
    gemm_f16<0, 256><<<g, 256, 0, stream>>>(hA, W2T, b2,  nullptr, hB, nullptr, B, H, H,  gx);
    gemm_f16<1, 256><<<g, 256, 0, stream>>>(hB, KW2T, Kb2, p2,     hA, nullptr, B, H, H,  gx);
  }
  {
    int gx = OUT / 128, gy = B / 128;
    dim3 g(gx * gy);
    gemm_f16<2, 128><<<g, 256, 0, stream>>>(hA, W3T, b3, nullptr, nullptr, (float*)d_out, B, OUT, H, gx);
  }
}

// Round 7
// 227.672 us; speedup vs baseline: 1.5008x; 1.0633x over previous
//
#include <hip/hip_runtime.h>
#include <math.h>

// B=4096, IN=1024, H=2048, OUT=1024
// cosmic layer == broadcast prob[r] = (1/H)*(prod_{d,k} cos(cw[d,r,k]))^2
// Network = 6 fp16-MFMA GEMMs (16x16x32) with fused bias/relu/tanh epilogues.
//
// r7: m201-style 2-phase-per-K-tile schedule. BM x 128 tile, BK=64, 512 thr
// (8 waves 4Mx2N, per-wave 64x64, conflict-free 16x16 frags), tri-buffered
// LDS, register-double-buffered fragments (MFMA consumes the set loaded one
// phase earlier), counted lgkmcnt(8)/vmcnt(3) (T4), per-phase double barrier
// (wave alternation), setprio around MFMA clusters (T5), XOR-swizzle
// both-sides (T2/rule 21), XCD swizzle (T1).

typedef _Float16 f16;
typedef _Float16 f16x8 __attribute__((ext_vector_type(8)));
typedef _Float16 f16x4 __attribute__((ext_vector_type(4)));
typedef float f32x4 __attribute__((ext_vector_type(4)));

#define GLD16(gp, lp) __builtin_amdgcn_global_load_lds( \
    (const __attribute__((address_space(1))) unsigned int*)(gp), \
    (__attribute__((address_space(3))) unsigned int*)(lp), 16, 0, 0)

__device__ __forceinline__ float tanh_fast(float x) {
  return 1.0f - 2.0f / (__expf(2.0f * x) + 1.0f);
}

// ---------------- fp32 -> fp16 cast ----------------
__global__ void cast_f32_f16(const float* __restrict__ in, f16* __restrict__ out, int n4) {
  int i = blockIdx.x * 256 + threadIdx.x;
  if (i < n4) {
    float4 v = ((const float4*)in)[i];
    f16x4 o = { (f16)v.x, (f16)v.y, (f16)v.z, (f16)v.w };
    ((f16x4*)out)[i] = o;
  }
}

// ------- merged cast+transpose, vectorized: 32(K) x 64(N) f32 tiles -------
struct TD { const float* src; f16* dst; int K; int N; };
struct TD6 { TD d[6]; };

__global__ void cast_transpose6(TD6 a) {
  TD d = a.d[blockIdx.z];
  const int bx = blockIdx.x * 64;   // N
  const int by = blockIdx.y * 32;   // K
  if (bx >= d.N || by >= d.K) return;
  __shared__ float tile[32][68];
  const int t = threadIdx.x;
#pragma unroll
  for (int pass = 0; pass < 2; ++pass) {
    int idx = t + pass * 256;
    int row = idx >> 4;
    int c4  = (idx & 15) * 4;
    float4 v = *(const float4*)&d.src[(size_t)(by + row) * d.N + bx + c4];
    *(float4*)&tile[row][c4] = v;
  }
  __syncthreads();
  const int nl = t >> 2;
  const int k8 = (t & 3) * 8;
  f16x8 o;
#pragma unroll
  for (int j = 0; j < 8; ++j) o[j] = (f16)tile[k8 + j][nl];
  *(f16x8*)&d.dst[(size_t)(bx + nl) * d.K + by + k8] = o;
}

// ---------------- cosmic prob, 2-pass ----------------
__global__ void cosmic_pp(const float* __restrict__ cw, float* __restrict__ pp, int H) {
  int i = blockIdx.x * 256 + threadIdx.x;   // i = d*H + r
  if (i >= 8 * H) return;
  const float* a = cw + (size_t)i * H;
  pp[i] = cosf(a[0]) * cosf(a[1]) * cosf(a[2]);
}
__global__ void cosmic_fin(const float* __restrict__ pp, float* __restrict__ prob, int H) {
  int r = blockIdx.x * 256 + threadIdx.x;
  if (r >= H) return;
  float p = 1.0f;
#pragma unroll
  for (int d = 0; d < 8; ++d) p *= pp[d * H + r];
  prob[r] = p * p / (float)H;
}

// ---------------- fp16 MFMA GEMM (16x16x32), 2-phase pipeline ----------------
// A: (M,K) f16 row-major. BT: (N,K) f16 row-major.
// EPI 0: relu->f16  1: tanh(+prob)->f16  2: relu->f32
template <int EPI, int BM>
__global__ __launch_bounds__(512, 2)
void gemm_f16(const f16* __restrict__ A, const f16* __restrict__ BT,
              const float* __restrict__ bias, const float* __restrict__ prob,
              f16* __restrict__ Ch, float* __restrict__ Cf,
              int M, int N, int K, int GX) {
  constexpr int ASZ  = BM * 64;         // f16 per A buffer (BK=64)
  constexpr int BSZ  = 128 * 64;        // f16 per B buffer
  constexpr int MR   = BM / 64;         // A frag repeats per wave (4 or 2)
  constexpr int RA   = ASZ / 4096;      // A stage rounds (512 thr * 8 f16)
  constexpr int RB   = BSZ / 4096;      // B stage rounds (2)
  constexpr int R    = RA + RB;         // rounds per tile (6 or 4)
  constexpr int HALF = R / 2;           // rounds per phase (3 or 2)
  constexpr int LG   = MR + 4;          // ds_reads per frag set
  __shared__ f16 lds[3 * (ASZ + BSZ)];  // 144 KB (BM=256) / 96 KB (BM=128)
  f16* As = lds;
  f16* Bs = lds + 3 * ASZ;

  const int t = threadIdx.x;

  // XCD-aware swizzle (nwg % 8 == 0 for all our grids)
  const int nwg = gridDim.x;
  const int bid = blockIdx.x;
  const int swz = (bid & 7) * (nwg >> 3) + (bid >> 3);
  const int bx = swz % GX;
  const int by = swz / GX;
  const int m0 = by * BM;
  const int n0 = bx * 128;

  // staging round q: LDS dest linear; XOR swizzle (chunk ^= row&7) applied
  // to the GLOBAL source (rule 21).
  auto stage_round = [&](int kt, int buf, int q) {
    const int k0 = kt << 6;
    if (q < RA) {
      int F = q * 4096 + t * 8;
      int r = F >> 6, c = (F >> 3) & 7;
      GLD16(A + (size_t)(m0 + r) * K + k0 + ((c ^ (r & 7)) << 3), As + buf * ASZ + F);
    } else {
      int F = (q - RA) * 4096 + t * 8;
      int r = F >> 6, c = (F >> 3) & 7;
      GLD16(BT + (size_t)(n0 + r) * K + k0 + ((c ^ (r & 7)) << 3), Bs + buf * BSZ + F);
    }
  };

  const int wave = t >> 6, lane = t & 63;
  const int wr = wave >> 1, wc = wave & 1;   // 4M x 2N waves; wave = (BM/4) x 64
  const int l16 = lane & 15, kq = lane >> 4;

  f32x4 acc[MR][4] = {};
  f16x8 a0[MR], b0[4], a1[MR], b1[4];

  auto read_set = [&](int buf, int s, f16x8* ra, f16x8* rb) {
#pragma unroll
    for (int mr = 0; mr < MR; ++mr) {
      int row = wr * (BM / 4) + mr * 16 + l16;
      ra[mr] = *(const f16x8*)&As[buf * ASZ + row * 64 + (((s * 4 + kq) ^ (row & 7)) << 3)];
    }
#pragma unroll
    for (int nr = 0; nr < 4; ++nr) {
      int row = wc * 64 + nr * 16 + l16;
      rb[nr] = *(const f16x8*)&Bs[buf * BSZ + row * 64 + (((s * 4 + kq) ^ (row & 7)) << 3)];
    }
  };
  auto mfma_set = [&](const f16x8* ra, const f16x8* rb) {
    __builtin_amdgcn_s_setprio(1);
#pragma unroll
    for (int mr = 0; mr < MR; ++mr)
#pragma unroll
      for (int nr = 0; nr < 4; ++nr)
        acc[mr][nr] = __builtin_amdgcn_mfma_f32_16x16x32_f16(ra[mr], rb[nr], acc[mr][nr], 0, 0, 0);
    __builtin_amdgcn_s_setprio(0);
  };

  const int nt = K >> 6;
  // prologue: stage tiles 0,1; load frag set0 = (tile0, s0)
#pragma unroll
  for (int q = 0; q < R; ++q) stage_round(0, 0, q);
#pragma unroll
  for (int q = 0; q < R; ++q) stage_round(1, 1, q);
  asm volatile("s_waitcnt vmcnt(%0)" :: "i"(R) : "memory");  // tile0 staged
  __builtin_amdgcn_s_barrier();
  read_set(0, 0, a0, b0);

  int cur = 0;
  for (int kt = 0; kt < nt - 1; ++kt) {
    int nxt = cur + 1; if (nxt == 3) nxt = 0;
    int sb  = cur + 2; if (sb  >= 3) sb -= 3;
    const bool st = (kt + 2 < nt);
    // ---- phase A: read set1(cur,s1) | stage first half kt+2 | MFMA set0
    read_set(cur, 1, a1, b1);
    if (st) {
#pragma unroll
      for (int q = 0; q < HALF; ++q) stage_round(kt + 2, sb, q);
    }
    __builtin_amdgcn_s_barrier();
    asm volatile("s_waitcnt lgkmcnt(%0)" :: "i"(LG) : "memory");  // set0 ready
    __builtin_amdgcn_sched_barrier(0);
    mfma_set(a0, b0);
    __builtin_amdgcn_s_barrier();
    // ---- phase B: vmcnt(tile kt+1 staged) | stage 2nd half | read set0(nxt,s0) | MFMA set1
    if (st) {
      asm volatile("s_waitcnt vmcnt(%0)" :: "i"(HALF) : "memory");
#pragma unroll
      for (int q = HALF; q < R; ++q) stage_round(kt + 2, sb, q);
    } else {
      asm volatile("s_waitcnt vmcnt(0)" ::: "memory");
    }
    __builtin_amdgcn_s_barrier();   // all waves' tile-(kt+1) staging visible
    read_set(nxt, 0, a0, b0);
    asm volatile("s_waitcnt lgkmcnt(%0)" :: "i"(LG) : "memory");  // set1 ready
    __builtin_amdgcn_sched_barrier(0);
    mfma_set(a1, b1);
    __builtin_amdgcn_s_barrier();
    cur = nxt;
  }
  // ---- tail: tile nt-1 (set0 already loaded)
  read_set(cur, 1, a1, b1);
  asm volatile("s_waitcnt lgkmcnt(%0)" :: "i"(LG) : "memory");
  __builtin_amdgcn_sched_barrier(0);
  mfma_set(a0, b0);
  asm volatile("s_waitcnt lgkmcnt(0)" ::: "memory");
  __builtin_amdgcn_sched_barrier(0);
  mfma_set(a1, b1);

  // epilogue: 16x16 C/D layout col=lane&15, row=(lane>>4)*4+q
#pragma unroll
  for (int nr = 0; nr < 4; ++nr) {
    const int col = n0 + wc * 64 + nr * 16 + l16;
    float bn = bias[col];
    if (EPI == 1) bn += prob[col];
#pragma unroll
    for (int mr = 0; mr < MR; ++mr) {
      const int rbase = m0 + wr * (BM / 4) + mr * 16 + kq * 4;
#pragma unroll
      for (int q = 0; q < 4; ++q) {
        float v = acc[mr][nr][q] + bn;
        if (EPI == 1) v = tanh_fast(v);
        else v = fmaxf(v, 0.0f);
        if (EPI == 2) Cf[(size_t)(rbase + q) * N + col] = v;
        else Ch[(size_t)(rbase + q) * N + col] = (f16)v;
      }
    }
  }
}

extern "C" void kernel_launch(void* const* d_in, const int* in_sizes, int n_in,
                              void* d_out, int out_size, void* d_ws, size_t ws_size,
                              hipStream_t stream) {
  const float* x   = (const float*)d_in[0];
  const float* W0  = (const float*)d_in[1];
  const float* b0  = (const float*)d_in[2];
  const float* W1  = (const float*)d_in[3];
  const float* b1  = (const float*)d_in[4];
  const float* cw1 = (const float*)d_in[5];
  const float* KW1 = (const float*)d_in[7];
  const float* Kb1 = (const float*)d_in[8];
  const float* W2  = (const float*)d_in[9];
  const float* b2  = (const float*)d_in[10];
  const float* cw2 = (const float*)d_in[11];
  const float* KW2 = (const float*)d_in[13];
  const float* Kb2 = (const float*)d_in[14];
  const float* W3  = (const float*)d_in[15];
  const float* b3  = (const float*)d_in[16];

  const int B = 4096, IN = 1024, H = 2048, OUT = 1024;

  char* ws = (char*)d_ws;
  size_t off = 0;
  auto alloc = [&](size_t bytes) {
    char* p = ws + off;
    off = (off + bytes + 255) & ~(size_t)255;
    return p;
  };
  f16* xh    = (f16*)alloc((size_t)B * IN * 2);
  f16* W0T   = (f16*)alloc((size_t)H * IN * 2);
  f16* W1T   = (f16*)alloc((size_t)H * H * 2);
  f16* KW1T  = (f16*)alloc((size_t)H * H * 2);
  f16* W2T   = (f16*)alloc((size_t)H * H * 2);
  f16* KW2T  = (f16*)alloc((size_t)H * H * 2);
  f16* W3T   = (f16*)alloc((size_t)OUT * H * 2);
  f16* hA    = (f16*)alloc((size_t)B * H * 2);
  f16* hB    = (f16*)alloc((size_t)B * H * 2);
  float* p1  = (float*)alloc((size_t)H * 4);
  float* p2  = (float*)alloc((size_t)H * 4);
  float* pp  = (float*)alloc((size_t)8 * H * 4);
  (void)ws_size;

  cast_f32_f16<<<(B * IN / 4 + 255) / 256, 256, 0, stream>>>(x, xh, B * IN / 4);

  TD6 td;
  td.d[0] = { W0,  W0T,  IN, H };
  td.d[1] = { W1,  W1T,  H,  H };
  td.d[2] = { KW1, KW1T, H,  H };
  td.d[3] = { W2,  W2T,  H,  H };
  td.d[4] = { KW2, KW2T, H,  H };
  td.d[5] = { W3,  W3T,  H,  OUT };
  cast_transpose6<<<dim3(H / 64, H / 32, 6), 256, 0, stream>>>(td);

  cosmic_pp<<<(8 * H + 255) / 256, 256, 0, stream>>>(cw1, pp, H);
  cosmic_fin<<<(H + 255) / 256, 256, 0, stream>>>(pp, p1, H);
  cosmic_pp<<<(8 * H + 255) / 256, 256, 0, stream>>>(cw2, pp, H);
  cosmic_fin<<<(H + 255) / 256, 256, 0, stream>>>(pp, p2, H);

  // G0-G4: BM=256 (grid 16x16=256). G5: BM=128 (grid 8x32=256).
  {
    int gx = H / 128, gy = B / 256;
    dim3 g(gx * gy);
    gemm_f16<0, 256><<<g, 512, 0, stream>>>(xh, W0T, b0,  nullptr, hA, nullptr, B, H, IN, gx);
    gemm_f16<0, 256><<<g, 512, 0, stream>>>(hA, W1T, b1,  nullptr, hB, nullptr, B, H, H,  gx);
    gemm_f16<1, 256><<<g, 512, 0, stream>>>(hB, KW1T, Kb1, p1,     hA, nullptr, B, H, H,  gx);
    gemm_f16<0, 256><<<g, 512, 0, stream>>>(hA, W2T, b2,  nullptr, hB, nullptr, B, H, H,  gx);
    gemm_f16<1, 256><<<g, 512, 0, stream>>>(hB, KW2T, Kb2, p2,     hA, nullptr, B, H, H,  gx);
  }
  {
    int gx = OUT / 128, gy = B / 128;
    dim3 g(gx * gy);
    gemm_f16<2, 128><<<g, 512, 0, stream>>>(hA, W3T, b3, nullptr, nullptr, (float*)d_out, B, OUT, H, gx);
  }
}